// Round 12
// baseline (335.530 us; speedup 1.0000x reference)
//
#include <hip/hip_runtime.h>
#include <math.h>

#define B_ 16
#define T_ 1024
#define D_ 96
#define L_ 6
#define NH_ 6
#define HS_ 16
#define FF_ 384

typedef _Float16 h4 __attribute__((ext_vector_type(4)));
typedef float f4 __attribute__((ext_vector_type(4)));

#define MFMA16 __builtin_amdgcn_mfma_f32_16x16x16f16

// packed f16 W^T buffer segment offsets (in halves)
#define OFF_GO   0
#define OFF_QKV  9216
#define OFF_PROJ 175104
#define OFF_FF1  230400
#define OFF_FF2  451584
#define OFF_ACT  672768
#define PACK_TOTAL 674304

// Q weights pre-scaled by 1/sqrt(16) * log2(e) so attn uses exp2 directly.
#define QSCALE 0.3606737602222409f

// ---------- pack all weights -> f16 W^T [N][K] ----------
__global__ __launch_bounds__(256) void pack_all_kernel(
    const float* __restrict__ w_go, const float* __restrict__ wq,
    const float* __restrict__ wk, const float* __restrict__ wv,
    const float* __restrict__ w_proj, const float* __restrict__ w_ff1,
    const float* __restrict__ w_ff2, const float* __restrict__ w_act,
    _Float16* __restrict__ P) {
  int i = blockIdx.x * 256 + threadIdx.x;
  if (i >= PACK_TOTAL) return;
  float v;
  if (i < OFF_QKV) {                       // w_go [96k][96n] -> [n][k]
    int o = i, n = o / 96, k = o % 96;
    v = w_go[k * 96 + n];
  } else if (i < OFF_PROJ) {               // wq/wk/wv -> [l][c=288][d=96]
    int o = i - OFF_QKV;
    int l = o / 27648, r = o % 27648, c = r / 96, d = r % 96;
    int which = c / 96;
    int hc = c % 96, h = hc >> 4, jx = hc & 15;
    const float* s = (which == 0) ? wq : (which == 1 ? wk : wv);
    v = s[((l * NH_ + h) * 96 + d) * 16 + jx];
    if (which == 0) v *= QSCALE;
  } else if (i < OFF_FF1) {                // w_proj [l][96k][96n] -> [l][n][k]
    int o = i - OFF_PROJ;
    int l = o / 9216, r = o % 9216, n = r / 96, k = r % 96;
    v = w_proj[l * 9216 + k * 96 + n];
  } else if (i < OFF_FF2) {                // w_ff1 [l][96k][384n] -> [l][n][k]
    int o = i - OFF_FF1;
    int l = o / 36864, r = o % 36864, n = r / 96, k = r % 96;
    v = w_ff1[l * 36864 + k * 384 + n];
  } else if (i < OFF_ACT) {                // w_ff2 [l][384k][96n] -> [l][n][k]
    int o = i - OFF_FF2;
    int l = o / 36864, r = o % 36864, n = r / 384, k = r % 384;
    v = w_ff2[l * 36864 + k * 96 + n];
  } else {                                 // w_act [96k][16n] -> [n][k]
    int o = i - OFF_ACT;
    int n = o / 96, k = o % 96;
    v = w_act[k * 16 + n];
  }
  P[i] = (_Float16)v;
}

// ---------- fused layer kernel: attn + proj + MLP + (qkv|head) ----------
// 12 waves, 64 tokens/block as 4 16-row chunks of batch b: chunk indices
// {2j, 2j+1, 62-2j, 63-2j} (pairing balances causal attn cost: 33 tiles/wave).
// attn: wave (h=w>>1, p=w&1) does 2 chunks of 16 q-rows, out -> OSH.
// stage: wave (cf=w>>1, gh=w&1) owns col-frag cf for groups {2gh,2gh+1};
// ff1 frags {2w,2w+1} x 4 groups; ff2 full-K for own 2 groups; tail frag w
// (+ half V frag). LDS: XSH 0..15360 | OSH 15360..28672 | HSH 0..61440
// (overlays both, written after reads done) | LNS 61440..64512.
#define MODE_EMBED 0
#define MODE_MID 1
#define MODE_LAST 2

template <int MODE>
__global__ __launch_bounds__(768, 3) void layer_kernel(
    const float* __restrict__ goals, const float* __restrict__ obss,
    const float* __restrict__ pos, const float* __restrict__ b_go,
    const _Float16* __restrict__ Qs, const _Float16* __restrict__ Ks,
    const _Float16* __restrict__ Vs,
    const _Float16* __restrict__ Wp, const float* __restrict__ bp,
    float* __restrict__ x,
    const _Float16* __restrict__ W1, const float* __restrict__ b1,
    const _Float16* __restrict__ W2, const float* __restrict__ b2,
    const float* __restrict__ ln2g, const float* __restrict__ ln2b,
    const float* __restrict__ lntg, const float* __restrict__ lntb,
    const _Float16* __restrict__ Wtail, const float* __restrict__ btail,
    _Float16* __restrict__ Qd, _Float16* __restrict__ Kd,
    _Float16* __restrict__ Vd, float* __restrict__ out) {
  __shared__ float smemf[16128];  // 64512 B
#define XSH(g, row, c) ((_Float16*)smemf + (size_t)(g) * 1920 + (row) * 20 + (c))
#define OSH(row, c) ((_Float16*)smemf + 7680 + (size_t)(row) * 104 + (c))
#define HSH(g, f, r, c) ((_Float16*)smemf + (size_t)(g) * 7680 + ((f) * 16 + (r)) * 20 + (c))
#define LNS(g, wv, r, i2) smemf[15360 + (((g) * 6 + (wv)) * 16 + (r)) * 2 + (i2)]
  const int tid = threadIdx.x;
  const int w = tid >> 6, lane = tid & 63;
  const int lr = lane & 15, lg = lane >> 4;
  const int b = blockIdx.x >> 4, j = blockIdx.x & 15;
  const int cf = w >> 1, gh = w & 1;
  const f4 zero4 = {0.f, 0.f, 0.f, 0.f};
  // chunk row-index within batch for group g: m(g) = g<2 ? 2j+g : 60-2j+g
  const int gA = gh * 2, gB = gh * 2 + 1;
  const int mA = (gh == 0) ? (2 * j) : (62 - 2 * j);
  const int mB = (gh == 0) ? (2 * j + 1) : (63 - 2 * j);
  const int tA = mA * 16 + lr, tB = mB * 16 + lr;       // in-batch token
  const int tokA = b * 1024 + tA, tokB = b * 1024 + tB; // global token

  // ================= attention phase =================
  if constexpr (MODE != MODE_EMBED) {
    const int ah = w >> 1, ap = w & 1;
    const size_t bhoff = (size_t)(b * 6 + ah) * 16384;
    const _Float16* qp = Qs + bhoff;
    const _Float16* kb = Ks + bhoff;
    const _Float16* vb = Vs + bhoff;
#pragma unroll
    for (int cc = 0; cc < 2; ++cc) {
      int ga = (cc == 0) ? ap : 3 - ap;  // balanced: low chunk + high chunk
      int m = (ga < 2) ? (2 * j + ga) : (60 - 2 * j + ga);
      int base = ga * 16;
      int q0 = m * 16;
      h4 qf = *(const h4*)(qp + (size_t)(q0 + lr) * 16 + lg * 4);
      f4 O = zero4;
      float ls = 0.f;
      int nfull = m >> 1;
      h4 kc0 = *(const h4*)(kb + (size_t)lr * 16 + lg * 4);
      h4 kc1 = *(const h4*)(kb + (size_t)(16 + lr) * 16 + lg * 4);
      h4 vc0 = *(const h4*)(vb + (size_t)lr * 1024 + lg * 4);
      h4 vc1 = *(const h4*)(vb + (size_t)lr * 1024 + 16 + lg * 4);
      for (int tt = 0; tt < nfull; ++tt) {
        int s1 = tt * 32 + 32;
        h4 kn0 = *(const h4*)(kb + (size_t)(s1 + lr) * 16 + lg * 4);
        h4 kn1 = *(const h4*)(kb + (size_t)(s1 + 16 + lr) * 16 + lg * 4);
        h4 vn0 = *(const h4*)(vb + (size_t)lr * 1024 + s1 + lg * 4);
        h4 vn1 = *(const h4*)(vb + (size_t)lr * 1024 + s1 + 16 + lg * 4);
        f4 s0v = MFMA16(kc0, qf, zero4, 0, 0, 0);
        f4 s1v = MFMA16(kc1, qf, zero4, 0, 0, 0);
        float p0[4], p1[4];
#pragma unroll
        for (int r = 0; r < 4; ++r) {
          p0[r] = __builtin_amdgcn_exp2f(s0v[r]);
          p1[r] = __builtin_amdgcn_exp2f(s1v[r]);
          ls += p0[r] + p1[r];
        }
        h4 f0 = {(_Float16)p0[0], (_Float16)p0[1], (_Float16)p0[2], (_Float16)p0[3]};
        h4 f1 = {(_Float16)p1[0], (_Float16)p1[1], (_Float16)p1[2], (_Float16)p1[3]};
        O = MFMA16(f0, vc0, O, 0, 0, 0);
        O = MFMA16(f1, vc1, O, 0, 0, 0);
        kc0 = kn0; kc1 = kn1; vc0 = vn0; vc1 = vn1;
      }
      // tail tile at s0 = nfull*32
      if (m & 1) {  // kc0 full, kc1 causal-masked
        f4 s0v = MFMA16(kc0, qf, zero4, 0, 0, 0);
        f4 s1v = MFMA16(kc1, qf, zero4, 0, 0, 0);
        float p0[4], p1[4];
#pragma unroll
        for (int r = 0; r < 4; ++r) {
          p0[r] = __builtin_amdgcn_exp2f(s0v[r]);
          p1[r] = (lg * 4 + r <= lr) ? __builtin_amdgcn_exp2f(s1v[r]) : 0.f;
          ls += p0[r] + p1[r];
        }
        h4 f0 = {(_Float16)p0[0], (_Float16)p0[1], (_Float16)p0[2], (_Float16)p0[3]};
        h4 f1 = {(_Float16)p1[0], (_Float16)p1[1], (_Float16)p1[2], (_Float16)p1[3]};
        O = MFMA16(f0, vc0, O, 0, 0, 0);
        O = MFMA16(f1, vc1, O, 0, 0, 0);
      } else {      // half-tile, kc0 causal-masked
        f4 s0v = MFMA16(kc0, qf, zero4, 0, 0, 0);
        float p0[4];
#pragma unroll
        for (int r = 0; r < 4; ++r) {
          p0[r] = (lg * 4 + r <= lr) ? __builtin_amdgcn_exp2f(s0v[r]) : 0.f;
          ls += p0[r];
        }
        h4 f0 = {(_Float16)p0[0], (_Float16)p0[1], (_Float16)p0[2], (_Float16)p0[3]};
        O = MFMA16(f0, vc0, O, 0, 0, 0);
      }
      ls += __shfl_xor(ls, 16);
      ls += __shfl_xor(ls, 32);
      float li = 1.f / ls;
#pragma unroll
      for (int r = 0; r < 4; ++r) {
        float lb = __shfl(li, lg * 4 + r);
        *OSH(base + lg * 4 + r, ah * 16 + lr) = (_Float16)(O[r] * lb);
      }
    }
    __syncthreads();  // B0: OSH complete
  }

  // ================= stage =================
  f4 x1[2], xc[2];

  if constexpr (MODE == MODE_EMBED) {
    h4 ef[2][6];
#pragma unroll
    for (int i = 0; i < 2; ++i) {
      int t = i ? tB : tA;
#pragma unroll
      for (int st = 0; st < 6; ++st) {
        int k0 = st * 16 + lg * 4;
        f4 s4 = (st < 2)
            ? *(const f4*)(goals + b * 32 + k0)
            : *(const f4*)(obss + (size_t)(b * 1024 + t) * 64 + (k0 - 32));
        ef[i][st] = (h4){(_Float16)s4[0], (_Float16)s4[1], (_Float16)s4[2], (_Float16)s4[3]};
      }
    }
    h4 wf[6];
    const _Float16* wr = Wp + (size_t)(cf * 16 + lr) * 96 + lg * 4;
#pragma unroll
    for (int st = 0; st < 6; ++st) wf[st] = *(const h4*)(wr + st * 16);
    f4 bb = *(const f4*)(b_go + cf * 16 + lg * 4);
#pragma unroll
    for (int i = 0; i < 2; ++i) {
      int t = i ? tB : tA, tk = i ? tokB : tokA;
      f4 a = zero4;
#pragma unroll
      for (int st = 0; st < 6; ++st) a = MFMA16(wf[st], ef[i][st], a, 0, 0, 0);
      f4 pp = *(const f4*)(pos + (size_t)t * 96 + cf * 16 + lg * 4);
#pragma unroll
      for (int jj = 0; jj < 4; ++jj) xc[i][jj] = a[jj] + bb[jj] + pp[jj];
      *(f4*)(x + (size_t)tk * 96 + cf * 16 + lg * 4) = xc[i];
    }
  } else {
    // ---- proj + resid ----
    h4 obf[2][6];
#pragma unroll
    for (int i = 0; i < 2; ++i) {
      int Lrow = (i ? gB : gA) * 16 + lr;
#pragma unroll
      for (int st = 0; st < 6; ++st)
        obf[i][st] = *(const h4*)OSH(Lrow, st * 16 + lg * 4);
    }
    h4 wf[6];
    const _Float16* wr = Wp + (size_t)(cf * 16 + lr) * 96 + lg * 4;
#pragma unroll
    for (int st = 0; st < 6; ++st) wf[st] = *(const h4*)(wr + st * 16);
    f4 bb = *(const f4*)(bp + cf * 16 + lg * 4);
#pragma unroll
    for (int i = 0; i < 2; ++i) {
      f4 a = zero4;
#pragma unroll
      for (int st = 0; st < 6; ++st) a = MFMA16(wf[st], obf[i][st], a, 0, 0, 0);
      f4 xr = *(const f4*)(x + (size_t)(i ? tokB : tokA) * 96 + cf * 16 + lg * 4);
#pragma unroll
      for (int jj = 0; jj < 4; ++jj) x1[i][jj] = a[jj] + bb[jj] + xr[jj];
    }
    // ---- LN2 ----
#pragma unroll
    for (int i = 0; i < 2; ++i) {
      float s = x1[i][0] + x1[i][1] + x1[i][2] + x1[i][3];
      float sq = x1[i][0] * x1[i][0] + x1[i][1] * x1[i][1] +
                 x1[i][2] * x1[i][2] + x1[i][3] * x1[i][3];
      s += __shfl_xor(s, 16); sq += __shfl_xor(sq, 16);
      s += __shfl_xor(s, 32); sq += __shfl_xor(sq, 32);
      if (lane < 16) { LNS(i ? gB : gA, cf, lr, 0) = s; LNS(i ? gB : gA, cf, lr, 1) = sq; }
    }
    __syncthreads();  // B1
    {
      f4 g4 = *(const f4*)(ln2g + cf * 16 + lg * 4);
      f4 b4 = *(const f4*)(ln2b + cf * 16 + lg * 4);
#pragma unroll
      for (int i = 0; i < 2; ++i) {
        int g = i ? gB : gA;
        float s = 0.f, sq = 0.f;
#pragma unroll
        for (int wv = 0; wv < 6; ++wv) { s += LNS(g, wv, lr, 0); sq += LNS(g, wv, lr, 1); }
        float mean = s * (1.f / 96.f);
        float rs = rsqrtf(sq * (1.f / 96.f) - mean * mean + 1e-5f);
        h4 xn;
#pragma unroll
        for (int jj = 0; jj < 4; ++jj)
          xn[jj] = (_Float16)((x1[i][jj] - mean) * rs * g4[jj] + b4[jj]);
        *(h4*)XSH(g, cf * 16 + lr, lg * 4) = xn;
      }
    }
    __syncthreads();  // B2
    h4 xnf[4][6];
#pragma unroll
    for (int g = 0; g < 4; ++g)
#pragma unroll
      for (int st = 0; st < 6; ++st)
        xnf[g][st] = *(const h4*)XSH(g, st * 16 + lr, lg * 4);
    __syncthreads();  // B2b: XSH/OSH dead, HSH may overlay

    // ---- ff1 + relu -> HSH (frags 2w, 2w+1) ----
#pragma unroll
    for (int f = 0; f < 2; ++f) {
      int nf = w * 2 + f;
      h4 w1f[6];
      const _Float16* w1r = W1 + (size_t)(nf * 16 + lr) * 96 + lg * 4;
#pragma unroll
      for (int st = 0; st < 6; ++st) w1f[st] = *(const h4*)(w1r + st * 16);
      f4 b4 = *(const f4*)(b1 + nf * 16 + lg * 4);
#pragma unroll
      for (int g = 0; g < 4; ++g) {
        f4 h = zero4;
#pragma unroll
        for (int st = 0; st < 6; ++st) h = MFMA16(w1f[st], xnf[g][st], h, 0, 0, 0);
        h4 hv;
#pragma unroll
        for (int jj = 0; jj < 4; ++jj) hv[jj] = (_Float16)fmaxf(h[jj] + b4[jj], 0.f);
        *(h4*)HSH(g, nf, lr, lg * 4) = hv;
      }
    }
    // ---- ff2 ----
    h4 w2f[24];
    {
      const _Float16* w2r = W2 + (size_t)(cf * 16 + lr) * 384 + lg * 4;
#pragma unroll
      for (int f = 0; f < 24; ++f) w2f[f] = *(const h4*)(w2r + f * 16);
    }
    __syncthreads();  // B3
    {
      f4 b4 = *(const f4*)(b2 + cf * 16 + lg * 4);
#pragma unroll
      for (int i = 0; i < 2; ++i) {
        int g = i ? gB : gA;
        f4 y = zero4;
#pragma unroll
        for (int f = 0; f < 24; ++f) {
          h4 hv = *(const h4*)HSH(g, f, lr, lg * 4);
          y = MFMA16(w2f[f], hv, y, 0, 0, 0);
        }
#pragma unroll
        for (int jj = 0; jj < 4; ++jj) xc[i][jj] = x1[i][jj] + y[jj] + b4[jj];
        if constexpr (MODE != MODE_LAST)
          *(f4*)(x + (size_t)(i ? tokB : tokA) * 96 + cf * 16 + lg * 4) = xc[i];
      }
    }
  }

  // ---- tail LN on xc ----
#pragma unroll
  for (int i = 0; i < 2; ++i) {
    float s = xc[i][0] + xc[i][1] + xc[i][2] + xc[i][3];
    float sq = xc[i][0] * xc[i][0] + xc[i][1] * xc[i][1] +
               xc[i][2] * xc[i][2] + xc[i][3] * xc[i][3];
    s += __shfl_xor(s, 16); sq += __shfl_xor(sq, 16);
    s += __shfl_xor(s, 32); sq += __shfl_xor(sq, 32);
    if (lane < 16) { LNS(i ? gB : gA, cf, lr, 0) = s; LNS(i ? gB : gA, cf, lr, 1) = sq; }
  }
  __syncthreads();  // B4 (HSH reads done)
  {
    f4 g4 = *(const f4*)(lntg + cf * 16 + lg * 4);
    f4 b4 = *(const f4*)(lntb + cf * 16 + lg * 4);
#pragma unroll
    for (int i = 0; i < 2; ++i) {
      int g = i ? gB : gA;
      float s = 0.f, sq = 0.f;
#pragma unroll
      for (int wv = 0; wv < 6; ++wv) { s += LNS(g, wv, lr, 0); sq += LNS(g, wv, lr, 1); }
      float mean = s * (1.f / 96.f);
      float rs = rsqrtf(sq * (1.f / 96.f) - mean * mean + 1e-5f);
      h4 xn;
#pragma unroll
      for (int jj = 0; jj < 4; ++jj)
        xn[jj] = (_Float16)((xc[i][jj] - mean) * rs * g4[jj] + b4[jj]);
      *(h4*)XSH(g, cf * 16 + lr, lg * 4) = xn;
    }
  }
  __syncthreads();  // B5
  if constexpr (MODE == MODE_LAST) {
    if (w == 0) {
      h4 wt[6];
      const _Float16* wtr = Wtail + (size_t)lr * 96 + lg * 4;
#pragma unroll
      for (int st = 0; st < 6; ++st) wt[st] = *(const h4*)(wtr + st * 16);
      f4 bb = *(const f4*)(btail + lg * 4);
#pragma unroll
      for (int g = 0; g < 4; ++g) {
        int m = (g < 2) ? (2 * j + g) : (60 - 2 * j + g);
        int tk = b * 1024 + m * 16 + lr;
        f4 a = zero4;
#pragma unroll
        for (int st = 0; st < 6; ++st) {
          h4 xf = *(const h4*)XSH(g, st * 16 + lr, lg * 4);
          a = MFMA16(wt[st], xf, a, 0, 0, 0);
        }
        f4 o;
#pragma unroll
        for (int jj = 0; jj < 4; ++jj) o[jj] = a[jj] + bb[jj];
        *(f4*)(out + (size_t)tk * 16 + lg * 4) = o;
      }
    }
  } else {
    h4 xf[4][6];
#pragma unroll
    for (int g = 0; g < 4; ++g)
#pragma unroll
      for (int st = 0; st < 6; ++st)
        xf[g][st] = *(const h4*)XSH(g, st * 16 + lr, lg * 4);
    // frag fa = w: Q heads 0-5 (w<6) / K heads 0-5 (w>=6), all 4 groups
    {
      int nf = w;
      h4 wt[6];
      const _Float16* wtr = Wtail + (size_t)(nf * 16 + lr) * 96 + lg * 4;
#pragma unroll
      for (int st = 0; st < 6; ++st) wt[st] = *(const h4*)(wtr + st * 16);
      int hh = (w < 6) ? w : w - 6;
      _Float16* dbase = ((w < 6) ? Qd : Kd) + (size_t)(b * 6 + hh) * 16384;
#pragma unroll
      for (int g = 0; g < 4; ++g) {
        int m = (g < 2) ? (2 * j + g) : (60 - 2 * j + g);
        int t = m * 16 + lr;
        f4 a = zero4;
#pragma unroll
        for (int st = 0; st < 6; ++st) a = MFMA16(wt[st], xf[g][st], a, 0, 0, 0);
        h4 hv = {(_Float16)a[0], (_Float16)a[1], (_Float16)a[2], (_Float16)a[3]};
        *(h4*)(dbase + (size_t)t * 16 + lg * 4) = hv;
      }
    }
    // frag fb = V head (w<6 ? w : w-6), 2 groups each (split across wave pair)
    {
      int hb = (w < 6) ? w : w - 6;
      int nf = 12 + hb;
      h4 wt[6];
      const _Float16* wtr = Wtail + (size_t)(nf * 16 + lr) * 96 + lg * 4;
#pragma unroll
      for (int st = 0; st < 6; ++st) wt[st] = *(const h4*)(wtr + st * 16);
      _Float16* vbase = Vd + (size_t)(b * 6 + hb) * 16384;
      int gs = (w < 6) ? 0 : 2;
#pragma unroll
      for (int gi = 0; gi < 2; ++gi) {
        int g = gs + gi;
        int m = (g < 2) ? (2 * j + g) : (60 - 2 * j + g);
        int t = m * 16 + lr;
        f4 a = zero4;
#pragma unroll
        for (int st = 0; st < 6; ++st) a = MFMA16(wt[st], xf[g][st], a, 0, 0, 0);
#pragma unroll
        for (int r = 0; r < 4; ++r)
          vbase[(size_t)(lg * 4 + r) * 1024 + t] = (_Float16)a[r];
      }
    }
  }
#undef XSH
#undef OSH
#undef HSH
#undef LNS
}

extern "C" void kernel_launch(void* const* d_in, const int* in_sizes, int n_in,
                              void* d_out, int out_size, void* d_ws, size_t ws_size,
                              hipStream_t stream) {
  const float* goals   = (const float*)d_in[0];
  const float* obss    = (const float*)d_in[1];
  const float* w_go    = (const float*)d_in[2];
  const float* b_go    = (const float*)d_in[3];
  const float* pos_emb = (const float*)d_in[4];
  const float* wq      = (const float*)d_in[5];
  const float* wk      = (const float*)d_in[6];
  const float* wv      = (const float*)d_in[7];
  const float* w_proj  = (const float*)d_in[8];
  const float* b_proj  = (const float*)d_in[9];
  const float* ln1_g   = (const float*)d_in[10];
  const float* ln1_b   = (const float*)d_in[11];
  const float* ln2_g   = (const float*)d_in[12];
  const float* ln2_b   = (const float*)d_in[13];
  const float* w_ff1   = (const float*)d_in[14];
  const float* b_ff1   = (const float*)d_in[15];
  const float* w_ff2   = (const float*)d_in[16];
  const float* b_ff2   = (const float*)d_in[17];
  const float* lnf_g   = (const float*)d_in[18];
  const float* lnf_b   = (const float*)d_in[19];
  const float* w_act   = (const float*)d_in[20];
  const float* b_act   = (const float*)d_in[21];
  float* out = (float*)d_out;

  const int M = B_ * T_;  // 16384
  float* ws = (float*)d_ws;
  size_t off = 0;
  _Float16* P = (_Float16*)(ws + off); off += PACK_TOTAL / 2 + 64;
  float* x = ws + off; off += (size_t)M * 96;
  _Float16* Qb[2]; _Float16* Kb[2]; _Float16* Vb[2];
  for (int p = 0; p < 2; ++p) {
    Qb[p] = (_Float16*)(ws + off); off += (size_t)M * 48;  // [96 bh][1024][16] halves
    Kb[p] = (_Float16*)(ws + off); off += (size_t)M * 48;
    Vb[p] = (_Float16*)(ws + off); off += (size_t)M * 48;
  }

  pack_all_kernel<<<(PACK_TOTAL + 255) / 256, 256, 0, stream>>>(
      w_go, wq, wk, wv, w_proj, w_ff1, w_ff2, w_act, P);

  // embed + qkv(layer 0) -> parity 0
  layer_kernel<MODE_EMBED><<<256, 768, 0, stream>>>(
      goals, obss, pos_emb, b_go, nullptr, nullptr, nullptr,
      P + OFF_GO, nullptr, x, nullptr, nullptr, nullptr, nullptr,
      nullptr, nullptr, ln1_g, ln1_b, P + OFF_QKV, nullptr,
      Qb[0], Kb[0], Vb[0], nullptr);

  for (int l = 0; l < L_; ++l) {
    int sp = l & 1, dp = (l + 1) & 1;
    if (l < L_ - 1) {
      layer_kernel<MODE_MID><<<256, 768, 0, stream>>>(
          nullptr, nullptr, nullptr, nullptr, Qb[sp], Kb[sp], Vb[sp],
          P + OFF_PROJ + (size_t)l * 9216, b_proj + l * 96, x,
          P + OFF_FF1 + (size_t)l * 36864, b_ff1 + l * 384,
          P + OFF_FF2 + (size_t)l * 36864, b_ff2 + l * 96,
          ln2_g + l * 96, ln2_b + l * 96,
          ln1_g + (l + 1) * 96, ln1_b + (l + 1) * 96,
          P + OFF_QKV + (size_t)(l + 1) * 27648, nullptr,
          Qb[dp], Kb[dp], Vb[dp], nullptr);
    } else {
      layer_kernel<MODE_LAST><<<256, 768, 0, stream>>>(
          nullptr, nullptr, nullptr, nullptr, Qb[sp], Kb[sp], Vb[sp],
          P + OFF_PROJ + (size_t)l * 9216, b_proj + l * 96, x,
          P + OFF_FF1 + (size_t)l * 36864, b_ff1 + l * 384,
          P + OFF_FF2 + (size_t)l * 36864, b_ff2 + l * 96,
          ln2_g + l * 96, ln2_b + l * 96,
          lnf_g, lnf_b, P + OFF_ACT, b_act,
          nullptr, nullptr, nullptr, out);
    }
  }
}

// Round 13
// 298.100 us; speedup vs baseline: 1.1256x; 1.1256x over previous
//
#include <hip/hip_runtime.h>
#include <math.h>

#define B_ 16
#define T_ 1024
#define D_ 96
#define L_ 6
#define NH_ 6
#define HS_ 16
#define FF_ 384

typedef _Float16 h4 __attribute__((ext_vector_type(4)));
typedef float f4 __attribute__((ext_vector_type(4)));

#define MFMA16 __builtin_amdgcn_mfma_f32_16x16x16f16

// packed f16 W^T buffer segment offsets (in halves)
#define OFF_GO   0
#define OFF_QKV  9216
#define OFF_PROJ 175104
#define OFF_FF1  230400
#define OFF_FF2  451584
#define OFF_ACT  672768
#define PACK_TOTAL 674304

// Q weights pre-scaled by 1/sqrt(16) * log2(e) so attn uses exp2 directly.
#define QSCALE 0.3606737602222409f

// ---------- pack all weights -> f16 W^T [N][K] ----------
__global__ __launch_bounds__(256) void pack_all_kernel(
    const float* __restrict__ w_go, const float* __restrict__ wq,
    const float* __restrict__ wk, const float* __restrict__ wv,
    const float* __restrict__ w_proj, const float* __restrict__ w_ff1,
    const float* __restrict__ w_ff2, const float* __restrict__ w_act,
    _Float16* __restrict__ P) {
  int i = blockIdx.x * 256 + threadIdx.x;
  if (i >= PACK_TOTAL) return;
  float v;
  if (i < OFF_QKV) {                       // w_go [96k][96n] -> [n][k]
    int o = i, n = o / 96, k = o % 96;
    v = w_go[k * 96 + n];
  } else if (i < OFF_PROJ) {               // wq/wk/wv -> [l][c=288][d=96]
    int o = i - OFF_QKV;
    int l = o / 27648, r = o % 27648, c = r / 96, d = r % 96;
    int which = c / 96;
    int hc = c % 96, h = hc >> 4, jx = hc & 15;
    const float* s = (which == 0) ? wq : (which == 1 ? wk : wv);
    v = s[((l * NH_ + h) * 96 + d) * 16 + jx];
    if (which == 0) v *= QSCALE;
  } else if (i < OFF_FF1) {                // w_proj [l][96k][96n] -> [l][n][k]
    int o = i - OFF_PROJ;
    int l = o / 9216, r = o % 9216, n = r / 96, k = r % 96;
    v = w_proj[l * 9216 + k * 96 + n];
  } else if (i < OFF_FF2) {                // w_ff1 [l][96k][384n] -> [l][n][k]
    int o = i - OFF_FF1;
    int l = o / 36864, r = o % 36864, n = r / 96, k = r % 96;
    v = w_ff1[l * 36864 + k * 384 + n];
  } else if (i < OFF_ACT) {                // w_ff2 [l][384k][96n] -> [l][n][k]
    int o = i - OFF_FF2;
    int l = o / 36864, r = o % 36864, n = r / 384, k = r % 384;
    v = w_ff2[l * 36864 + k * 96 + n];
  } else {                                 // w_act [96k][16n] -> [n][k]
    int o = i - OFF_ACT;
    int n = o / 96, k = o % 96;
    v = w_act[k * 16 + n];
  }
  P[i] = (_Float16)v;
}

// ---------- stage kernel: 12 waves x 4 token-groups (64 tokens) ----------
// wave w: cf = w>>1 owns col-frag cf for groups {2gh, 2gh+1} (gh = w&1);
// ff1 hidden frags {2w, 2w+1} x 4 groups; tail Q/K frag w x 4 groups,
// V frag (w%6) x 2 groups. amdgpu_waves_per_eu(3,3) pins the occupancy
// target so the compiler keeps ~170 VGPR budget (r12's 64-VGPR trap).
#define MODE_EMBED 0
#define MODE_MID 1
#define MODE_LAST 2

template <int MODE>
__global__ __attribute__((amdgpu_flat_work_group_size(768, 768)))
__attribute__((amdgpu_waves_per_eu(3, 3)))
void stage12_kernel(
    const float* __restrict__ goals, const float* __restrict__ obss,
    const float* __restrict__ pos, const float* __restrict__ b_go,
    const _Float16* __restrict__ obh, const _Float16* __restrict__ Wp,
    const float* __restrict__ bp, float* __restrict__ x,
    const _Float16* __restrict__ W1, const float* __restrict__ b1,
    const _Float16* __restrict__ W2, const float* __restrict__ b2,
    const float* __restrict__ ln2g, const float* __restrict__ ln2b,
    const float* __restrict__ lntg, const float* __restrict__ lntb,
    const _Float16* __restrict__ Wtail, const float* __restrict__ btail,
    _Float16* __restrict__ qh, _Float16* __restrict__ kh,
    _Float16* __restrict__ vt, float* __restrict__ out) {
  __shared__ float smemf[16128];  // 64512 B
#define XSH(g, row, c) ((_Float16*)smemf + (size_t)(g) * 1920 + (row) * 20 + (c))
#define HSH(g, f, r, c) ((_Float16*)smemf + (size_t)(g) * 7680 + ((f) * 16 + (r)) * 20 + (c))
#define LNS(g, wv, r, i2) smemf[15360 + (((g) * 6 + (wv)) * 16 + (r)) * 2 + (i2)]
  const int tid = threadIdx.x;
  const int w = tid >> 6, lane = tid & 63;
  const int lr = lane & 15, lg = lane >> 4;
  const int row0 = blockIdx.x * 64;
  const int bidx = row0 >> 10;
  const int cf = w >> 1, gh = w & 1;
  const int gA = gh * 2, gB = gh * 2 + 1;
  const f4 zero4 = {0.f, 0.f, 0.f, 0.f};
  int tok[4], tt[4];
#pragma unroll
  for (int g = 0; g < 4; ++g) { tok[g] = row0 + g * 16 + lr; tt[g] = tok[g] & 1023; }
  const int tokA = tok[gA], tokB = tok[gB];

  f4 x1[2], xc[2];

  if constexpr (MODE == MODE_EMBED) {
    h4 ef[2][6];
#pragma unroll
    for (int i = 0; i < 2; ++i) {
      int t = tt[i ? gB : gA];
#pragma unroll
      for (int st = 0; st < 6; ++st) {
        int k0 = st * 16 + lg * 4;
        f4 s4 = (st < 2)
            ? *(const f4*)(goals + bidx * 32 + k0)
            : *(const f4*)(obss + (size_t)(bidx * 1024 + t) * 64 + (k0 - 32));
        ef[i][st] = (h4){(_Float16)s4[0], (_Float16)s4[1], (_Float16)s4[2], (_Float16)s4[3]};
      }
    }
    h4 wf[6];
    const _Float16* wr = Wp + (size_t)(cf * 16 + lr) * 96 + lg * 4;
#pragma unroll
    for (int st = 0; st < 6; ++st) wf[st] = *(const h4*)(wr + st * 16);
    f4 bb = *(const f4*)(b_go + cf * 16 + lg * 4);
#pragma unroll
    for (int i = 0; i < 2; ++i) {
      int t = tt[i ? gB : gA], tk = i ? tokB : tokA;
      f4 a = zero4;
#pragma unroll
      for (int st = 0; st < 6; ++st) a = MFMA16(wf[st], ef[i][st], a, 0, 0, 0);
      f4 pp = *(const f4*)(pos + (size_t)t * 96 + cf * 16 + lg * 4);
#pragma unroll
      for (int jj = 0; jj < 4; ++jj) xc[i][jj] = a[jj] + bb[jj] + pp[jj];
      *(f4*)(x + (size_t)tk * 96 + cf * 16 + lg * 4) = xc[i];
    }
  } else {
    // ---- proj + resid (own col-frag, own 2 groups) ----
    h4 obf[2][6];
#pragma unroll
    for (int i = 0; i < 2; ++i) {
      const _Float16* orow = obh + (size_t)(i ? tokB : tokA) * 96 + lg * 4;
#pragma unroll
      for (int st = 0; st < 6; ++st) obf[i][st] = *(const h4*)(orow + st * 16);
    }
    h4 wf[6];
    const _Float16* wr = Wp + (size_t)(cf * 16 + lr) * 96 + lg * 4;
#pragma unroll
    for (int st = 0; st < 6; ++st) wf[st] = *(const h4*)(wr + st * 16);
    f4 bb = *(const f4*)(bp + cf * 16 + lg * 4);
#pragma unroll
    for (int i = 0; i < 2; ++i) {
      f4 a = zero4;
#pragma unroll
      for (int st = 0; st < 6; ++st) a = MFMA16(wf[st], obf[i][st], a, 0, 0, 0);
      f4 xr = *(const f4*)(x + (size_t)(i ? tokB : tokA) * 96 + cf * 16 + lg * 4);
#pragma unroll
      for (int jj = 0; jj < 4; ++jj) x1[i][jj] = a[jj] + bb[jj] + xr[jj];
    }
    // ---- LN2 ----
#pragma unroll
    for (int i = 0; i < 2; ++i) {
      float s = x1[i][0] + x1[i][1] + x1[i][2] + x1[i][3];
      float sq = x1[i][0] * x1[i][0] + x1[i][1] * x1[i][1] +
                 x1[i][2] * x1[i][2] + x1[i][3] * x1[i][3];
      s += __shfl_xor(s, 16); sq += __shfl_xor(sq, 16);
      s += __shfl_xor(s, 32); sq += __shfl_xor(sq, 32);
      if (lane < 16) { LNS(i ? gB : gA, cf, lr, 0) = s; LNS(i ? gB : gA, cf, lr, 1) = sq; }
    }
    __syncthreads();  // B1
    {
      f4 g4 = *(const f4*)(ln2g + cf * 16 + lg * 4);
      f4 b4 = *(const f4*)(ln2b + cf * 16 + lg * 4);
#pragma unroll
      for (int i = 0; i < 2; ++i) {
        int g = i ? gB : gA;
        float s = 0.f, sq = 0.f;
#pragma unroll
        for (int wv = 0; wv < 6; ++wv) { s += LNS(g, wv, lr, 0); sq += LNS(g, wv, lr, 1); }
        float mean = s * (1.f / 96.f);
        float rs = rsqrtf(sq * (1.f / 96.f) - mean * mean + 1e-5f);
        h4 xn;
#pragma unroll
        for (int jj = 0; jj < 4; ++jj)
          xn[jj] = (_Float16)((x1[i][jj] - mean) * rs * g4[jj] + b4[jj]);
        *(h4*)XSH(g, cf * 16 + lr, lg * 4) = xn;
      }
    }
    __syncthreads();  // B2
    h4 xnf[4][6];
#pragma unroll
    for (int g = 0; g < 4; ++g)
#pragma unroll
      for (int st = 0; st < 6; ++st)
        xnf[g][st] = *(const h4*)XSH(g, st * 16 + lr, lg * 4);
    __syncthreads();  // B2b: xn fully read, HSH may overlay

    // ---- ff1 + relu -> HSH (frags 2w, 2w+1 x 4 groups) ----
#pragma unroll
    for (int f = 0; f < 2; ++f) {
      int nf = w * 2 + f;
      h4 w1f[6];
      const _Float16* w1r = W1 + (size_t)(nf * 16 + lr) * 96 + lg * 4;
#pragma unroll
      for (int st = 0; st < 6; ++st) w1f[st] = *(const h4*)(w1r + st * 16);
      f4 b4 = *(const f4*)(b1 + nf * 16 + lg * 4);
#pragma unroll
      for (int g = 0; g < 4; ++g) {
        f4 h = zero4;
#pragma unroll
        for (int st = 0; st < 6; ++st) h = MFMA16(w1f[st], xnf[g][st], h, 0, 0, 0);
        h4 hv;
#pragma unroll
        for (int jj = 0; jj < 4; ++jj) hv[jj] = (_Float16)fmaxf(h[jj] + b4[jj], 0.f);
        *(h4*)HSH(g, nf, lr, lg * 4) = hv;
      }
    }
    // ---- ff2 (own col-frag, own 2 groups, full K=384) ----
    h4 w2f[24];
    {
      const _Float16* w2r = W2 + (size_t)(cf * 16 + lr) * 384 + lg * 4;
#pragma unroll
      for (int f = 0; f < 24; ++f) w2f[f] = *(const h4*)(w2r + f * 16);
    }
    __syncthreads();  // B3: all hf written
    {
      f4 b4 = *(const f4*)(b2 + cf * 16 + lg * 4);
#pragma unroll
      for (int i = 0; i < 2; ++i) {
        int g = i ? gB : gA;
        f4 y = zero4;
#pragma unroll
        for (int f = 0; f < 24; ++f) {
          h4 hv = *(const h4*)HSH(g, f, lr, lg * 4);
          y = MFMA16(w2f[f], hv, y, 0, 0, 0);
        }
#pragma unroll
        for (int jj = 0; jj < 4; ++jj) xc[i][jj] = x1[i][jj] + y[jj] + b4[jj];
        if constexpr (MODE != MODE_LAST)
          *(f4*)(x + (size_t)(i ? tokB : tokA) * 96 + cf * 16 + lg * 4) = xc[i];
      }
    }
  }

  // ---- tail LN on xc (own 2 groups) ----
#pragma unroll
  for (int i = 0; i < 2; ++i) {
    float s = xc[i][0] + xc[i][1] + xc[i][2] + xc[i][3];
    float sq = xc[i][0] * xc[i][0] + xc[i][1] * xc[i][1] +
               xc[i][2] * xc[i][2] + xc[i][3] * xc[i][3];
    s += __shfl_xor(s, 16); sq += __shfl_xor(sq, 16);
    s += __shfl_xor(s, 32); sq += __shfl_xor(sq, 32);
    if (lane < 16) { LNS(i ? gB : gA, cf, lr, 0) = s; LNS(i ? gB : gA, cf, lr, 1) = sq; }
  }
  __syncthreads();  // B4 (HSH reads done before XSH overlays)
  {
    f4 g4 = *(const f4*)(lntg + cf * 16 + lg * 4);
    f4 b4 = *(const f4*)(lntb + cf * 16 + lg * 4);
#pragma unroll
    for (int i = 0; i < 2; ++i) {
      int g = i ? gB : gA;
      float s = 0.f, sq = 0.f;
#pragma unroll
      for (int wv = 0; wv < 6; ++wv) { s += LNS(g, wv, lr, 0); sq += LNS(g, wv, lr, 1); }
      float mean = s * (1.f / 96.f);
      float rs = rsqrtf(sq * (1.f / 96.f) - mean * mean + 1e-5f);
      h4 xn;
#pragma unroll
      for (int jj = 0; jj < 4; ++jj)
        xn[jj] = (_Float16)((xc[i][jj] - mean) * rs * g4[jj] + b4[jj]);
      *(h4*)XSH(g, cf * 16 + lr, lg * 4) = xn;
    }
  }
  __syncthreads();  // B5
  if constexpr (MODE == MODE_LAST) {
    if (w == 0) {
      h4 wt[6];
      const _Float16* wtr = Wtail + (size_t)lr * 96 + lg * 4;
#pragma unroll
      for (int st = 0; st < 6; ++st) wt[st] = *(const h4*)(wtr + st * 16);
      f4 bb = *(const f4*)(btail + lg * 4);
#pragma unroll
      for (int g = 0; g < 4; ++g) {
        f4 a = zero4;
#pragma unroll
        for (int st = 0; st < 6; ++st) {
          h4 xf = *(const h4*)XSH(g, st * 16 + lr, lg * 4);
          a = MFMA16(wt[st], xf, a, 0, 0, 0);
        }
        f4 o;
#pragma unroll
        for (int jj = 0; jj < 4; ++jj) o[jj] = a[jj] + bb[jj];
        *(f4*)(out + (size_t)(row0 + g * 16 + lr) * 16 + lg * 4) = o;
      }
    }
  } else {
    h4 xf[4][6];
#pragma unroll
    for (int g = 0; g < 4; ++g)
#pragma unroll
      for (int st = 0; st < 6; ++st)
        xf[g][st] = *(const h4*)XSH(g, st * 16 + lr, lg * 4);
    // Q/K frag nf = w (Q: w<6, K: w>=6), all 4 groups
    {
      int nf = w;
      h4 wt[6];
      const _Float16* wtr = Wtail + (size_t)(nf * 16 + lr) * 96 + lg * 4;
#pragma unroll
      for (int st = 0; st < 6; ++st) wt[st] = *(const h4*)(wtr + st * 16);
      int hh = (w < 6) ? w : w - 6;
      _Float16* dbase = ((w < 6) ? qh : kh) + (size_t)(bidx * 6 + hh) * 16384;
#pragma unroll
      for (int g = 0; g < 4; ++g) {
        f4 a = zero4;
#pragma unroll
        for (int st = 0; st < 6; ++st) a = MFMA16(wt[st], xf[g][st], a, 0, 0, 0);
        h4 hv = {(_Float16)a[0], (_Float16)a[1], (_Float16)a[2], (_Float16)a[3]};
        *(h4*)(dbase + (size_t)tt[g] * 16 + lg * 4) = hv;
      }
    }
    // V frag (w%6), 2 groups each (w<6: groups 0,1; w>=6: groups 2,3)
    {
      int hb = (w < 6) ? w : w - 6;
      int nf = 12 + hb;
      h4 wt[6];
      const _Float16* wtr = Wtail + (size_t)(nf * 16 + lr) * 96 + lg * 4;
#pragma unroll
      for (int st = 0; st < 6; ++st) wt[st] = *(const h4*)(wtr + st * 16);
      _Float16* vbase = vt + (size_t)(bidx * 6 + hb) * 16384;
      int gs = (w < 6) ? 0 : 2;
#pragma unroll
      for (int gi = 0; gi < 2; ++gi) {
        int g = gs + gi;
        f4 a = zero4;
#pragma unroll
        for (int st = 0; st < 6; ++st) a = MFMA16(wt[st], xf[g][st], a, 0, 0, 0);
#pragma unroll
        for (int r = 0; r < 4; ++r)
          vbase[(size_t)(lg * 4 + r) * 1024 + tt[g]] = (_Float16)a[r];
      }
    }
  }
#undef XSH
#undef HSH
#undef LNS
}

// ---------- MFMA f16 flash attention: 64 q-rows/wave ----------
// grid (96 bh, 4), 4 waves. qb mirrored across waves so every block does
// exactly 68 tile-visits. 4 16-row subtiles share each K/V tile load
// (4 loads -> 16 MFMAs in the hot loop). Fixed-max softmax (exp2, Q
// pre-scaled); diagonal peeled into 2 explicit tiles.
__global__ __launch_bounds__(256, 4) void attn_mfma_kernel(
    const _Float16* __restrict__ Qh, const _Float16* __restrict__ Kh,
    const _Float16* __restrict__ Vt, _Float16* __restrict__ obh) {
  int bh = blockIdx.x;
  int w = threadIdx.x >> 6;
  int lane = threadIdx.x & 63;
  int y = blockIdx.y;
  int qb = (w < 2) ? (w * 4 + y) : (15 - ((w - 2) * 4 + y));  // 0..15
  int q0 = qb * 64;
  int lr = lane & 15;
  int lg = lane >> 4;

  const _Float16* qp = Qh + (size_t)bh * 16384;
  const _Float16* kb = Kh + (size_t)bh * 16384;
  const _Float16* vb = Vt + (size_t)bh * 16384;

  h4 qf[4];
#pragma unroll
  for (int u = 0; u < 4; ++u)
    qf[u] = *(const h4*)(qp + (size_t)(q0 + u * 16 + lr) * 16 + lg * 4);
  f4 O[4] = {{0.f,0.f,0.f,0.f},{0.f,0.f,0.f,0.f},{0.f,0.f,0.f,0.f},{0.f,0.f,0.f,0.f}};
  float ls[4] = {0.f, 0.f, 0.f, 0.f};
  const f4 zero4 = {0.f, 0.f, 0.f, 0.f};

  h4 kc0, kc1, vc0, vc1;
  kc0 = *(const h4*)(kb + (size_t)lr * 16 + lg * 4);
  kc1 = *(const h4*)(kb + (size_t)(16 + lr) * 16 + lg * 4);
  vc0 = *(const h4*)(vb + (size_t)lr * 1024 + lg * 4);
  vc1 = *(const h4*)(vb + (size_t)lr * 1024 + 16 + lg * 4);

  // hot loop: 2*qb full tiles, no masking
  for (int tt = 0; tt < 2 * qb; ++tt) {
    int s1 = tt * 32 + 32;
    h4 kn0 = *(const h4*)(kb + (size_t)(s1 + lr) * 16 + lg * 4);
    h4 kn1 = *(const h4*)(kb + (size_t)(s1 + 16 + lr) * 16 + lg * 4);
    h4 vn0 = *(const h4*)(vb + (size_t)lr * 1024 + s1 + lg * 4);
    h4 vn1 = *(const h4*)(vb + (size_t)lr * 1024 + s1 + 16 + lg * 4);
#pragma unroll
    for (int u = 0; u < 4; ++u) {
      f4 s0v = MFMA16(kc0, qf[u], zero4, 0, 0, 0);
      f4 s1v = MFMA16(kc1, qf[u], zero4, 0, 0, 0);
      float p0[4], p1[4];
#pragma unroll
      for (int r = 0; r < 4; ++r) {
        p0[r] = __builtin_amdgcn_exp2f(s0v[r]);
        p1[r] = __builtin_amdgcn_exp2f(s1v[r]);
        ls[u] += p0[r] + p1[r];
      }
      h4 f0 = {(_Float16)p0[0], (_Float16)p0[1], (_Float16)p0[2], (_Float16)p0[3]};
      h4 f1 = {(_Float16)p1[0], (_Float16)p1[1], (_Float16)p1[2], (_Float16)p1[3]};
      O[u] = MFMA16(f0, vc0, O[u], 0, 0, 0);
      O[u] = MFMA16(f1, vc1, O[u], 0, 0, 0);
    }
    kc0 = kn0; kc1 = kn1; vc0 = vn0; vc1 = vn1;
  }

  // diag tile A (s0 = q0): u0 h0 masked; u1 h0 full, h1 masked; u2,u3 full
  {
#pragma unroll
    for (int u = 0; u < 4; ++u) {
      f4 s0v = MFMA16(kc0, qf[u], zero4, 0, 0, 0);
      float p0[4];
      if (u == 0) {
#pragma unroll
        for (int r = 0; r < 4; ++r) {
          p0[r] = (lg * 4 + r <= lr) ? __builtin_amdgcn_exp2f(s0v[r]) : 0.f;
          ls[u] += p0[r];
        }
      } else {
#pragma unroll
        for (int r = 0; r < 4; ++r) {
          p0[r] = __builtin_amdgcn_exp2f(s0v[r]);
          ls[u] += p0[r];
        }
      }
      h4 f0 = {(_Float16)p0[0], (_Float16)p0[1], (_Float16)p0[2], (_Float16)p0[3]};
      O[u] = MFMA16(f0, vc0, O[u], 0, 0, 0);
      if (u >= 1) {
        f4 s1v = MFMA16(kc1, qf[u], zero4, 0, 0, 0);
        float p1[4];
        if (u == 1) {
#pragma unroll
          for (int r = 0; r < 4; ++r) {
            p1[r] = (lg * 4 + r <= lr) ? __builtin_amdgcn_exp2f(s1v[r]) : 0.f;
            ls[u] += p1[r];
          }
        } else {
#pragma unroll
          for (int r = 0; r < 4; ++r) {
            p1[r] = __builtin_amdgcn_exp2f(s1v[r]);
            ls[u] += p1[r];
          }
        }
        h4 f1 = {(_Float16)p1[0], (_Float16)p1[1], (_Float16)p1[2], (_Float16)p1[3]};
        O[u] = MFMA16(f1, vc1, O[u], 0, 0, 0);
      }
    }
  }
  // diag tile B (s0 = q0+32): u2 h0 masked; u3 h0 full, h1 masked
  {
    int s0 = q0 + 32;
    kc0 = *(const h4*)(kb + (size_t)(s0 + lr) * 16 + lg * 4);
    kc1 = *(const h4*)(kb + (size_t)(s0 + 16 + lr) * 16 + lg * 4);
    vc0 = *(const h4*)(vb + (size_t)lr * 1024 + s0 + lg * 4);
    vc1 = *(const h4*)(vb + (size_t)lr * 1024 + s0 + 16 + lg * 4);
    // u = 2: half0 masked
    {
      f4 s0v = MFMA16(kc0, qf[2], zero4, 0, 0, 0);
      float p0[4];
#pragma unroll
      for (int r = 0; r < 4; ++r) {
        p0[r] = (lg * 4 + r <= lr) ? __builtin_amdgcn_exp2f(s0v[r]) : 0.f;
        ls[2] += p0[r];
      }
      h4 f0 = {(_Float16)p0[0], (_Float16)p0[1], (_Float16)p0[2], (_Float16)p0[3]};
      O[2] = MFMA16(f0, vc0, O[2], 0, 0, 0);
    }
    // u = 3: half0 full, half1 masked
    {
      f4 s0v = MFMA16(kc0, qf[3], zero4, 0, 0, 0);
      f4 s1v = MFMA16(kc1, qf[3], zero4, 0, 0, 0);
      float p0[4], p1[4];
#pragma unroll
      for (int r = 0; r < 4; ++r) {
        p0[r] = __builtin_amdgcn_exp2f(s0v[r]);
        p1[r] = (lg * 4 + r <= lr) ? __builtin_amdgcn_exp2f(s1v[r]) : 0.f;
        ls[3] += p0[r] + p1[r];
      }
      h4 f0 = {(_Float16)p0[0], (_Float16)p0[1], (_Float16)p0[2], (_Float16)p0[3]};
      h4 f1 = {(_Float16)p1[0], (_Float16)p1[1], (_Float16)p1[2], (_Float16)p1[3]};
      O[3] = MFMA16(f0, vc0, O[3], 0, 0, 0);
      O[3] = MFMA16(f1, vc1, O[3], 0, 0, 0);
    }
  }

  int b = bh / NH_, h = bh % NH_;
#pragma unroll
  for (int u = 0; u < 4; ++u) {
    ls[u] += __shfl_xor(ls[u], 16);
    ls[u] += __shfl_xor(ls[u], 32);
    float li = 1.f / ls[u];
#pragma unroll
    for (int r = 0; r < 4; ++r) {
      float lb = __shfl(li, lg * 4 + r);
      int q = q0 + u * 16 + lg * 4 + r;
      obh[(size_t)(b * 1024 + q) * 96 + h * 16 + lr] = (_Float16)(O[u][r] * lb);
    }
  }
}

extern "C" void kernel_launch(void* const* d_in, const int* in_sizes, int n_in,
                              void* d_out, int out_size, void* d_ws, size_t ws_size,
                              hipStream_t stream) {
  const float* goals   = (const float*)d_in[0];
  const float* obss    = (const float*)d_in[1];
  const float* w_go    = (const float*)d_in[2];
  const float* b_go    = (const float*)d_in[3];
  const float* pos_emb = (const float*)d_in[4];
  const float* wq      = (const float*)d_in[5];
  const float* wk      = (const float*)d_in[6];
  const float* wv      = (const float*)d_in[7];
  const float* w_proj  = (const float*)d_in[8];
  const float* b_proj  = (const float*)d_in[9];
  const float* ln1_g   = (const float*)d_in[10];
  const float* ln1_b   = (const float*)d_in[11];
  const float* ln2_g   = (const float*)d_in[12];
  const float* ln2_b   = (const float*)d_in[13];
  const float* w_ff1   = (const float*)d_in[14];
  const float* b_ff1   = (const float*)d_in[15];
  const float* w_ff2   = (const float*)d_in[16];
  const float* b_ff2   = (const float*)d_in[17];
  const float* lnf_g   = (const float*)d_in[18];
  const float* lnf_b   = (const float*)d_in[19];
  const float* w_act   = (const float*)d_in[20];
  const float* b_act   = (const float*)d_in[21];
  float* out = (float*)d_out;

  const int M = B_ * T_;  // 16384
  float* ws = (float*)d_ws;
  size_t off = 0;
  _Float16* P = (_Float16*)(ws + off); off += PACK_TOTAL / 2 + 64;
  float* x = ws + off; off += (size_t)M * 96;
  _Float16* obh = (_Float16*)(ws + off); off += (size_t)M * 48;
  _Float16* Qh = (_Float16*)(ws + off); off += (size_t)M * 48;
  _Float16* Kh = (_Float16*)(ws + off); off += (size_t)M * 48;
  _Float16* Vt = (_Float16*)(ws + off); off += (size_t)M * 48;

  pack_all_kernel<<<(PACK_TOTAL + 255) / 256, 256, 0, stream>>>(
      w_go, wq, wk, wv, w_proj, w_ff1, w_ff2, w_act, P);

  // embed + qkv(layer 0)
  stage12_kernel<MODE_EMBED><<<M / 64, 768, 0, stream>>>(
      goals, obss, pos_emb, b_go, nullptr, P + OFF_GO, nullptr, x,
      nullptr, nullptr, nullptr, nullptr, nullptr, nullptr,
      ln1_g, ln1_b, P + OFF_QKV, nullptr, Qh, Kh, Vt, nullptr);

  for (int l = 0; l < L_; ++l) {
    attn_mfma_kernel<<<dim3(B_ * NH_, 4), 256, 0, stream>>>(Qh, Kh, Vt, obh);
    if (l < L_ - 1) {
      stage12_kernel<MODE_MID><<<M / 64, 768, 0, stream>>>(
          nullptr, nullptr, nullptr, nullptr, obh,
          P + OFF_PROJ + (size_t)l * 9216, b_proj + l * 96, x,
          P + OFF_FF1 + (size_t)l * 36864, b_ff1 + l * 384,
          P + OFF_FF2 + (size_t)l * 36864, b_ff2 + l * 96,
          ln2_g + l * 96, ln2_b + l * 96,
          ln1_g + (l + 1) * 96, ln1_b + (l + 1) * 96,
          P + OFF_QKV + (size_t)(l + 1) * 27648, nullptr, Qh, Kh, Vt, nullptr);
    } else {
      stage12_kernel<MODE_LAST><<<M / 64, 768, 0, stream>>>(
          nullptr, nullptr, nullptr, nullptr, obh,
          P + OFF_PROJ + (size_t)l * 9216, b_proj + l * 96, x,
          P + OFF_FF1 + (size_t)l * 36864, b_ff1 + l * 384,
          P + OFF_FF2 + (size_t)l * 36864, b_ff2 + l * 96,
          ln2_g + l * 96, ln2_b + l * 96,
          lnf_g, lnf_b, P + OFF_ACT, b_act, nullptr, nullptr, nullptr, out);
    }
  }
}

// Round 15
// 265.610 us; speedup vs baseline: 1.2632x; 1.1223x over previous
//
#include <hip/hip_runtime.h>
#include <math.h>

#define B_ 16
#define T_ 1024
#define D_ 96
#define L_ 6
#define NH_ 6
#define HS_ 16
#define FF_ 384

typedef _Float16 h4 __attribute__((ext_vector_type(4)));
typedef __fp16 g2 __attribute__((ext_vector_type(2)));
typedef __fp16 g4 __attribute__((ext_vector_type(4)));
typedef float f4 __attribute__((ext_vector_type(4)));

#define MFMA16 __builtin_amdgcn_mfma_f32_16x16x16f16

// packed f16 W^T buffer segment offsets (in halves)
#define OFF_GO   0
#define OFF_QKV  9216
#define OFF_PROJ 175104
#define OFF_FF1  230400
#define OFF_FF2  451584
#define OFF_ACT  672768
#define PACK_TOTAL 674304

// Q weights pre-scaled by 1/sqrt(16) * log2(e) so attn uses exp2 directly.
#define QSCALE 0.3606737602222409f

static __device__ __forceinline__ h4 pk4(const float* p) {
  g2 lo = __builtin_amdgcn_cvt_pkrtz(p[0], p[1]);
  g2 hi = __builtin_amdgcn_cvt_pkrtz(p[2], p[3]);
  g4 r4 = __builtin_shufflevector(lo, hi, 0, 1, 2, 3);
  return __builtin_bit_cast(h4, r4);
}

// ---------- pack all weights -> f16 W^T [N][K] ----------
__global__ __launch_bounds__(256) void pack_all_kernel(
    const float* __restrict__ w_go, const float* __restrict__ wq,
    const float* __restrict__ wk, const float* __restrict__ wv,
    const float* __restrict__ w_proj, const float* __restrict__ w_ff1,
    const float* __restrict__ w_ff2, const float* __restrict__ w_act,
    _Float16* __restrict__ P) {
  int i = blockIdx.x * 256 + threadIdx.x;
  if (i >= PACK_TOTAL) return;
  float v;
  if (i < OFF_QKV) {                       // w_go [96k][96n] -> [n][k]
    int o = i, n = o / 96, k = o % 96;
    v = w_go[k * 96 + n];
  } else if (i < OFF_PROJ) {               // wq/wk/wv -> [l][c=288][d=96]
    int o = i - OFF_QKV;
    int l = o / 27648, r = o % 27648, c = r / 96, d = r % 96;
    int which = c / 96;
    int hc = c % 96, h = hc >> 4, jx = hc & 15;
    const float* s = (which == 0) ? wq : (which == 1 ? wk : wv);
    v = s[((l * NH_ + h) * 96 + d) * 16 + jx];
    if (which == 0) v *= QSCALE;
  } else if (i < OFF_FF1) {                // w_proj [l][96k][96n] -> [l][n][k]
    int o = i - OFF_PROJ;
    int l = o / 9216, r = o % 9216, n = r / 96, k = r % 96;
    v = w_proj[l * 9216 + k * 96 + n];
  } else if (i < OFF_FF2) {                // w_ff1 [l][96k][384n] -> [l][n][k]
    int o = i - OFF_FF1;
    int l = o / 36864, r = o % 36864, n = r / 96, k = r % 96;
    v = w_ff1[l * 36864 + k * 384 + n];
  } else if (i < OFF_ACT) {                // w_ff2 [l][384k][96n] -> [l][n][k]
    int o = i - OFF_FF2;
    int l = o / 36864, r = o % 36864, n = r / 384, k = r % 384;
    v = w_ff2[l * 36864 + k * 96 + n];
  } else {                                 // w_act [96k][16n] -> [n][k]
    int o = i - OFF_ACT;
    int n = o / 96, k = o % 96;
    v = w_act[k * 16 + n];
  }
  P[i] = (_Float16)v;
}

// ---------- fused stage kernel: 6 waves x 4 token-groups (64 tokens) ------
template <bool EMBED, bool HEAD>
__global__ __launch_bounds__(384, 1) void stage_kernel(
    const float* __restrict__ goals, const float* __restrict__ obss,
    const float* __restrict__ pos, const float* __restrict__ b_go,
    const _Float16* __restrict__ obh, const _Float16* __restrict__ Wp,
    const float* __restrict__ bp, float* __restrict__ x,
    const _Float16* __restrict__ W1, const float* __restrict__ b1,
    const _Float16* __restrict__ W2, const float* __restrict__ b2,
    const float* __restrict__ ln2g, const float* __restrict__ ln2b,
    const float* __restrict__ lntg, const float* __restrict__ lntb,
    const _Float16* __restrict__ Wtail, const float* __restrict__ btail,
    _Float16* __restrict__ qh, _Float16* __restrict__ kh,
    _Float16* __restrict__ vt, float* __restrict__ out) {
  __shared__ float smemf[16128];  // 64512 B
#define XSH(g, row, c) ((_Float16*)smemf + (size_t)(g) * 1920 + (row) * 20 + (c))
#define HSH(g, f, r, c) ((_Float16*)smemf + (size_t)(g) * 7680 + ((f) * 16 + (r)) * 20 + (c))
#define LNS(g, w, r, i) smemf[15360 + (((g) * 6 + (w)) * 16 + (r)) * 2 + (i)]
  const int tid = threadIdx.x;
  const int wave = tid >> 6, lane = tid & 63;
  const int lr = lane & 15, lg = lane >> 4;
  const int row0 = blockIdx.x * 64;
  const int bidx = row0 >> 10;
  const int cfo = wave;  // owned col-frag 0..5
  const f4 zero4 = {0.f, 0.f, 0.f, 0.f};
  int tok[4], tt[4];
#pragma unroll
  for (int g = 0; g < 4; ++g) { tok[g] = row0 + g * 16 + lr; tt[g] = tok[g] & 1023; }

  f4 xc[4], x1[4];

  if constexpr (EMBED) {
    h4 ef[4][6];
#pragma unroll
    for (int st = 0; st < 2; ++st) {
      f4 s4 = *(const f4*)(goals + bidx * 32 + st * 16 + lg * 4);
      h4 e = (h4){(_Float16)s4[0], (_Float16)s4[1], (_Float16)s4[2], (_Float16)s4[3]};
#pragma unroll
      for (int g = 0; g < 4; ++g) ef[g][st] = e;
    }
#pragma unroll
    for (int g = 0; g < 4; ++g)
#pragma unroll
      for (int st = 2; st < 6; ++st) {
        f4 s4 = *(const f4*)(obss + (size_t)(bidx * 1024 + tt[g]) * 64 +
                             (st - 2) * 16 + lg * 4);
        ef[g][st] = (h4){(_Float16)s4[0], (_Float16)s4[1], (_Float16)s4[2], (_Float16)s4[3]};
      }
    h4 wf[6];
    const _Float16* wrow = Wp + (size_t)(cfo * 16 + lr) * 96 + lg * 4;
#pragma unroll
    for (int st = 0; st < 6; ++st) wf[st] = *(const h4*)(wrow + st * 16);
    f4 bb = *(const f4*)(b_go + cfo * 16 + lg * 4);
#pragma unroll
    for (int g = 0; g < 4; ++g) {
      f4 a = zero4;
#pragma unroll
      for (int st = 0; st < 6; ++st) a = MFMA16(wf[st], ef[g][st], a, 0, 0, 0);
      f4 pp = *(const f4*)(pos + (size_t)tt[g] * 96 + cfo * 16 + lg * 4);
#pragma unroll
      for (int j = 0; j < 4; ++j) xc[g][j] = a[j] + bb[j] + pp[j];
      *(f4*)(x + (size_t)tok[g] * 96 + cfo * 16 + lg * 4) = xc[g];
    }
  } else {
    // ---- proj + resid (own 1 col-frag, 4 groups) ----
    h4 obf[4][6];
#pragma unroll
    for (int g = 0; g < 4; ++g) {
      const _Float16* orow = obh + (size_t)tok[g] * 96 + lg * 4;
#pragma unroll
      for (int st = 0; st < 6; ++st) obf[g][st] = *(const h4*)(orow + st * 16);
    }
    h4 wf[6];
    const _Float16* wrow = Wp + (size_t)(cfo * 16 + lr) * 96 + lg * 4;
#pragma unroll
    for (int st = 0; st < 6; ++st) wf[st] = *(const h4*)(wrow + st * 16);
    f4 bb = *(const f4*)(bp + cfo * 16 + lg * 4);
#pragma unroll
    for (int g = 0; g < 4; ++g) {
      f4 a = zero4;
#pragma unroll
      for (int st = 0; st < 6; ++st) a = MFMA16(wf[st], obf[g][st], a, 0, 0, 0);
      f4 xr = *(const f4*)(x + (size_t)tok[g] * 96 + cfo * 16 + lg * 4);
#pragma unroll
      for (int j = 0; j < 4; ++j) x1[g][j] = a[j] + bb[j] + xr[j];
    }
    // ---- LN2 partials ----
#pragma unroll
    for (int g = 0; g < 4; ++g) {
      float s = x1[g][0] + x1[g][1] + x1[g][2] + x1[g][3];
      float sq = x1[g][0] * x1[g][0] + x1[g][1] * x1[g][1] +
                 x1[g][2] * x1[g][2] + x1[g][3] * x1[g][3];
      s += __shfl_xor(s, 16); sq += __shfl_xor(sq, 16);
      s += __shfl_xor(s, 32); sq += __shfl_xor(sq, 32);
      if (lane < 16) { LNS(g, wave, lr, 0) = s; LNS(g, wave, lr, 1) = sq; }
    }
    __syncthreads();  // B1
    {
      f4 gg4 = *(const f4*)(ln2g + cfo * 16 + lg * 4);
      f4 b4 = *(const f4*)(ln2b + cfo * 16 + lg * 4);
#pragma unroll
      for (int g = 0; g < 4; ++g) {
        float s = 0.f, sq = 0.f;
#pragma unroll
        for (int w = 0; w < 6; ++w) { s += LNS(g, w, lr, 0); sq += LNS(g, w, lr, 1); }
        float mean = s * (1.f / 96.f);
        float rs = rsqrtf(sq * (1.f / 96.f) - mean * mean + 1e-5f);
        h4 xn;
#pragma unroll
        for (int j = 0; j < 4; ++j)
          xn[j] = (_Float16)((x1[g][j] - mean) * rs * gg4[j] + b4[j]);
        *(h4*)XSH(g, cfo * 16 + lr, lg * 4) = xn;
      }
    }
    __syncthreads();  // B2
    h4 xnf[4][6];
#pragma unroll
    for (int g = 0; g < 4; ++g)
#pragma unroll
      for (int st = 0; st < 6; ++st)
        xnf[g][st] = *(const h4*)XSH(g, st * 16 + lr, lg * 4);
    __syncthreads();  // B2b (xn fully read before HSH overlays it)

    // ---- ff1 + relu -> HSH (own 4 hidden frags) ----
#pragma unroll
    for (int f = 0; f < 4; ++f) {
      int nf = wave * 4 + f;
      h4 w1f[6];
      const _Float16* wr = W1 + (size_t)(nf * 16 + lr) * 96 + lg * 4;
#pragma unroll
      for (int st = 0; st < 6; ++st) w1f[st] = *(const h4*)(wr + st * 16);
      f4 b4 = *(const f4*)(b1 + nf * 16 + lg * 4);
#pragma unroll
      for (int g = 0; g < 4; ++g) {
        f4 h = zero4;
#pragma unroll
        for (int st = 0; st < 6; ++st) h = MFMA16(w1f[st], xnf[g][st], h, 0, 0, 0);
        h4 hv;
#pragma unroll
        for (int j = 0; j < 4; ++j) hv[j] = (_Float16)fmaxf(h[j] + b4[j], 0.f);
        *(h4*)HSH(g, nf, lr, lg * 4) = hv;
      }
    }
    // ---- ff2 (own 1 output frag, full K=384 from HSH) ----
    h4 w2f[24];
    {
      const _Float16* wr = W2 + (size_t)(cfo * 16 + lr) * 384 + lg * 4;
#pragma unroll
      for (int f = 0; f < 24; ++f) w2f[f] = *(const h4*)(wr + f * 16);
    }
    __syncthreads();  // B3 (all hf written)
    {
      f4 b4 = *(const f4*)(b2 + cfo * 16 + lg * 4);
#pragma unroll
      for (int g = 0; g < 4; ++g) {
        f4 y = zero4;
#pragma unroll
        for (int f = 0; f < 24; ++f) {
          h4 hv = *(const h4*)HSH(g, f, lr, lg * 4);
          y = MFMA16(w2f[f], hv, y, 0, 0, 0);
        }
#pragma unroll
        for (int j = 0; j < 4; ++j) xc[g][j] = x1[g][j] + y[j] + b4[j];
        if constexpr (!HEAD)
          *(f4*)(x + (size_t)tok[g] * 96 + cfo * 16 + lg * 4) = xc[g];
      }
    }
  }

  // ---- tail LN on xc ----
#pragma unroll
  for (int g = 0; g < 4; ++g) {
    float s = xc[g][0] + xc[g][1] + xc[g][2] + xc[g][3];
    float sq = xc[g][0] * xc[g][0] + xc[g][1] * xc[g][1] +
               xc[g][2] * xc[g][2] + xc[g][3] * xc[g][3];
    s += __shfl_xor(s, 16); sq += __shfl_xor(sq, 16);
    s += __shfl_xor(s, 32); sq += __shfl_xor(sq, 32);
    if (lane < 16) { LNS(g, wave, lr, 0) = s; LNS(g, wave, lr, 1) = sq; }
  }
  __syncthreads();  // B4 (also: all HSH reads done before XSH overlays)
  {
    f4 gg4 = *(const f4*)(lntg + cfo * 16 + lg * 4);
    f4 b4 = *(const f4*)(lntb + cfo * 16 + lg * 4);
#pragma unroll
    for (int g = 0; g < 4; ++g) {
      float s = 0.f, sq = 0.f;
#pragma unroll
      for (int w = 0; w < 6; ++w) { s += LNS(g, w, lr, 0); sq += LNS(g, w, lr, 1); }
      float mean = s * (1.f / 96.f);
      float rs = rsqrtf(sq * (1.f / 96.f) - mean * mean + 1e-5f);
      h4 xn;
#pragma unroll
      for (int j = 0; j < 4; ++j)
        xn[j] = (_Float16)((xc[g][j] - mean) * rs * gg4[j] + b4[j]);
      *(h4*)XSH(g, cfo * 16 + lr, lg * 4) = xn;
    }
  }
  __syncthreads();  // B5
  if constexpr (HEAD) {
    if (wave == 0) {
      h4 wt[6];
      const _Float16* wr = Wtail + (size_t)lr * 96 + lg * 4;
#pragma unroll
      for (int st = 0; st < 6; ++st) wt[st] = *(const h4*)(wr + st * 16);
      f4 bb = *(const f4*)(btail + lg * 4);
#pragma unroll
      for (int g = 0; g < 4; ++g) {
        f4 a = zero4;
#pragma unroll
        for (int st = 0; st < 6; ++st) {
          h4 xf = *(const h4*)XSH(g, st * 16 + lr, lg * 4);
          a = MFMA16(wt[st], xf, a, 0, 0, 0);
        }
        f4 o;
#pragma unroll
        for (int j = 0; j < 4; ++j) o[j] = a[j] + bb[j];
        *(f4*)(out + (size_t)tok[g] * 16 + lg * 4) = o;
      }
    }
  } else {
    h4 xf[4][6];
#pragma unroll
    for (int g = 0; g < 4; ++g)
#pragma unroll
      for (int st = 0; st < 6; ++st)
        xf[g][st] = *(const h4*)XSH(g, st * 16 + lr, lg * 4);
    // tail frags: nf = wave*3 + f; Q:0-5 K:6-11 V:12-17
#pragma unroll
    for (int f = 0; f < 3; ++f) {
      int nf = wave * 3 + f;
      h4 wt[6];
      const _Float16* wr = Wtail + (size_t)(nf * 16 + lr) * 96 + lg * 4;
#pragma unroll
      for (int st = 0; st < 6; ++st) wt[st] = *(const h4*)(wr + st * 16);
#pragma unroll
      for (int g = 0; g < 4; ++g) {
        f4 a = zero4;
#pragma unroll
        for (int st = 0; st < 6; ++st) a = MFMA16(wt[st], xf[g][st], a, 0, 0, 0);
        if (nf < 12) {  // Q or K: [bh][t][16]
          int h = nf < 6 ? nf : nf - 6;
          _Float16* dst = (nf < 6 ? qh : kh) +
                          (size_t)(bidx * NH_ + h) * 16384 + (size_t)tt[g] * 16 + lg * 4;
          h4 hv = {(_Float16)a[0], (_Float16)a[1], (_Float16)a[2], (_Float16)a[3]};
          *(h4*)dst = hv;
        } else {        // V: [bh][d][1024]
          _Float16* dst = vt + (size_t)(bidx * NH_ + (nf - 12)) * 16384 +
                          (size_t)(lg * 4) * 1024 + tt[g];
#pragma unroll
          for (int r = 0; r < 4; ++r) dst[(size_t)r * 1024] = (_Float16)a[r];
        }
      }
    }
  }
#undef XSH
#undef HSH
#undef LNS
}

// ---------- MFMA f16 flash attention: 32 q-rows/wave, fixed-max softmax ----
// Softmax denominators via ones-MFMA (S += mfma(P, ones)) on the matrix
// pipe: no per-element adds, no cross-lane reduce (S layout == O layout).
// f32->f16 packing via cvt_pkrtz (2 values/instr).
__global__ __launch_bounds__(256, 6) void attn_mfma_kernel(
    const _Float16* __restrict__ Qh, const _Float16* __restrict__ Kh,
    const _Float16* __restrict__ Vt, _Float16* __restrict__ obh) {
  int bh = blockIdx.x;
  int wave = threadIdx.x >> 6;
  int lane = threadIdx.x & 63;
  int qb = wave * 8 + blockIdx.y;    // 0..31
  int q0 = qb * 32;
  int lr = lane & 15;
  int lg = lane >> 4;

  const _Float16* qp = Qh + (size_t)bh * 16384;
  const _Float16* kb = Kh + (size_t)bh * 16384;
  const _Float16* vb = Vt + (size_t)bh * 16384;

  h4 qf0 = *(const h4*)(qp + (size_t)(q0 + lr) * 16 + lg * 4);
  h4 qf1 = *(const h4*)(qp + (size_t)(q0 + 16 + lr) * 16 + lg * 4);
  f4 O0 = {0.f, 0.f, 0.f, 0.f}, O1 = {0.f, 0.f, 0.f, 0.f};
  f4 S0 = {0.f, 0.f, 0.f, 0.f}, S1 = {0.f, 0.f, 0.f, 0.f};
  const f4 zero4 = {0.f, 0.f, 0.f, 0.f};
  const h4 ones = {(_Float16)1.f, (_Float16)1.f, (_Float16)1.f, (_Float16)1.f};

  h4 kc0, kc1, vc0, vc1, kn0, kn1, vn0, vn1;
  kc0 = *(const h4*)(kb + (size_t)lr * 16 + lg * 4);
  kc1 = *(const h4*)(kb + (size_t)(16 + lr) * 16 + lg * 4);
  vc0 = *(const h4*)(vb + (size_t)lr * 1024 + lg * 4);
  vc1 = *(const h4*)(vb + (size_t)lr * 1024 + 16 + lg * 4);

  // hot loop: tiles [0, q0), no masking
  for (int tt = 0; tt < qb; ++tt) {
    int s1 = tt * 32 + 32;
    kn0 = *(const h4*)(kb + (size_t)(s1 + lr) * 16 + lg * 4);
    kn1 = *(const h4*)(kb + (size_t)(s1 + 16 + lr) * 16 + lg * 4);
    vn0 = *(const h4*)(vb + (size_t)lr * 1024 + s1 + lg * 4);
    vn1 = *(const h4*)(vb + (size_t)lr * 1024 + s1 + 16 + lg * 4);

    f4 sa0 = MFMA16(kc0, qf0, zero4, 0, 0, 0);
    f4 sa1 = MFMA16(kc1, qf0, zero4, 0, 0, 0);
    f4 sb0 = MFMA16(kc0, qf1, zero4, 0, 0, 0);
    f4 sb1 = MFMA16(kc1, qf1, zero4, 0, 0, 0);
    float pa0[4], pa1[4], pb0[4], pb1[4];
#pragma unroll
    for (int r = 0; r < 4; ++r) {
      pa0[r] = __builtin_amdgcn_exp2f(sa0[r]);
      pa1[r] = __builtin_amdgcn_exp2f(sa1[r]);
      pb0[r] = __builtin_amdgcn_exp2f(sb0[r]);
      pb1[r] = __builtin_amdgcn_exp2f(sb1[r]);
    }
    h4 fa0 = pk4(pa0), fa1 = pk4(pa1), fb0 = pk4(pb0), fb1 = pk4(pb1);
    O0 = MFMA16(fa0, vc0, O0, 0, 0, 0);
    O0 = MFMA16(fa1, vc1, O0, 0, 0, 0);
    S0 = MFMA16(fa0, ones, S0, 0, 0, 0);
    S0 = MFMA16(fa1, ones, S0, 0, 0, 0);
    O1 = MFMA16(fb0, vc0, O1, 0, 0, 0);
    O1 = MFMA16(fb1, vc1, O1, 0, 0, 0);
    S1 = MFMA16(fb0, ones, S1, 0, 0, 0);
    S1 = MFMA16(fb1, ones, S1, 0, 0, 0);
    kc0 = kn0; kc1 = kn1; vc0 = vn0; vc1 = vn1;
  }

  // last tile [q0, q0+32): u0 sees kv[q0,q0+16) masked; u1 sees kv[q0,q0+16)
  // full plus kv[q0+16,q0+32) masked. masked p -> 0 (excluded from O and S).
  {
    f4 sa0 = MFMA16(kc0, qf0, zero4, 0, 0, 0);
    float pa0[4];
#pragma unroll
    for (int r = 0; r < 4; ++r)
      pa0[r] = (lg * 4 + r <= lr) ? __builtin_amdgcn_exp2f(sa0[r]) : 0.f;
    h4 fa0 = pk4(pa0);
    O0 = MFMA16(fa0, vc0, O0, 0, 0, 0);
    S0 = MFMA16(fa0, ones, S0, 0, 0, 0);

    f4 sb0 = MFMA16(kc0, qf1, zero4, 0, 0, 0);
    f4 sb1 = MFMA16(kc1, qf1, zero4, 0, 0, 0);
    float pb0[4], pb1[4];
#pragma unroll
    for (int r = 0; r < 4; ++r) {
      pb0[r] = __builtin_amdgcn_exp2f(sb0[r]);
      pb1[r] = (lg * 4 + r <= lr) ? __builtin_amdgcn_exp2f(sb1[r]) : 0.f;
    }
    h4 fb0 = pk4(pb0), fb1 = pk4(pb1);
    O1 = MFMA16(fb0, vc0, O1, 0, 0, 0);
    O1 = MFMA16(fb1, vc1, O1, 0, 0, 0);
    S1 = MFMA16(fb0, ones, S1, 0, 0, 0);
    S1 = MFMA16(fb1, ones, S1, 0, 0, 0);
  }

  // S0[r]/S1[r] hold the full causal row-sums for q = q0(+16)+lg*4+r,
  // replicated across all 16 cols -> aligned with O; no cross-lane needed.
  int b = bh / NH_, h = bh % NH_;
#pragma unroll
  for (int r = 0; r < 4; ++r) {
    int qa = q0 + lg * 4 + r;
    float li0 = __builtin_amdgcn_rcpf(S0[r]);
    float li1 = __builtin_amdgcn_rcpf(S1[r]);
    obh[(size_t)(b * 1024 + qa) * 96 + h * 16 + lr] = (_Float16)(O0[r] * li0);
    obh[(size_t)(b * 1024 + qa + 16) * 96 + h * 16 + lr] = (_Float16)(O1[r] * li1);
  }
}

extern "C" void kernel_launch(void* const* d_in, const int* in_sizes, int n_in,
                              void* d_out, int out_size, void* d_ws, size_t ws_size,
                              hipStream_t stream) {
  const float* goals   = (const float*)d_in[0];
  const float* obss    = (const float*)d_in[1];
  const float* w_go    = (const float*)d_in[2];
  const float* b_go    = (const float*)d_in[3];
  const float* pos_emb = (const float*)d_in[4];
  const float* wq      = (const float*)d_in[5];
  const float* wk      = (const float*)d_in[6];
  const float* wv      = (const float*)d_in[7];
  const float* w_proj  = (const float*)d_in[8];
  const float* b_proj  = (const float*)d_in[9];
  const float* ln1_g   = (const float*)d_in[10];
  const float* ln1_b   = (const float*)d_in[11];
  const float* ln2_g   = (const float*)d_in[12];
  const float* ln2_b   = (const float*)d_in[13];
  const float* w_ff1   = (const float*)d_in[14];
  const float* b_ff1   = (const float*)d_in[15];
  const float* w_ff2   = (const float*)d_in[16];
  const float* b_ff2   = (const float*)d_in[17];
  const float* lnf_g   = (const float*)d_in[18];
  const float* lnf_b   = (const float*)d_in[19];
  const float* w_act   = (const float*)d_in[20];
  const float* b_act   = (const float*)d_in[21];
  float* out = (float*)d_out;

  const int M = B_ * T_;  // 16384
  float* ws = (float*)d_ws;
  size_t off = 0;
  _Float16* P = (_Float16*)(ws + off); off += PACK_TOTAL / 2 + 64;
  float* x = ws + off; off += (size_t)M * 96;
  _Float16* obh = (_Float16*)(ws + off); off += (size_t)M * 48;
  _Float16* Qh = (_Float16*)(ws + off); off += (size_t)M * 48;
  _Float16* Kh = (_Float16*)(ws + off); off += (size_t)M * 48;
  _Float16* Vt = (_Float16*)(ws + off); off += (size_t)M * 48;

  pack_all_kernel<<<(PACK_TOTAL + 255) / 256, 256, 0, stream>>>(
      w_go, wq, wk, wv, w_proj, w_ff1, w_ff2, w_act, P);

  // embed + qkv(layer 0)
  stage_kernel<true, false><<<M / 64, 384, 0, stream>>>(
      goals, obss, pos_emb, b_go, nullptr, P + OFF_GO, nullptr, x,
      nullptr, nullptr, nullptr, nullptr, nullptr, nullptr,
      ln1_g, ln1_b, P + OFF_QKV, nullptr, Qh, Kh, Vt, nullptr);

  for (int l = 0; l < L_; ++l) {
    attn_mfma_kernel<<<dim3(B_ * NH_, 8), 256, 0, stream>>>(Qh, Kh, Vt, obh);
    if (l < L_ - 1) {
      stage_kernel<false, false><<<M / 64, 384, 0, stream>>>(
          nullptr, nullptr, nullptr, nullptr, obh,
          P + OFF_PROJ + (size_t)l * 9216, b_proj + l * 96, x,
          P + OFF_FF1 + (size_t)l * 36864, b_ff1 + l * 384,
          P + OFF_FF2 + (size_t)l * 36864, b_ff2 + l * 96,
          ln2_g + l * 96, ln2_b + l * 96,
          ln1_g + (l + 1) * 96, ln1_b + (l + 1) * 96,
          P + OFF_QKV + (size_t)(l + 1) * 27648, nullptr, Qh, Kh, Vt, nullptr);
    } else {
      stage_kernel<false, true><<<M / 64, 384, 0, stream>>>(
          nullptr, nullptr, nullptr, nullptr, obh,
          P + OFF_PROJ + (size_t)l * 9216, b_proj + l * 96, x,
          P + OFF_FF1 + (size_t)l * 36864, b_ff1 + l * 384,
          P + OFF_FF2 + (size_t)l * 36864, b_ff2 + l * 96,
          ln2_g + l * 96, ln2_b + l * 96,
          lnf_g, lnf_b, P + OFF_ACT, b_act, nullptr, nullptr, nullptr, out);
    }
  }
}